// Round 3
// baseline (391.595 us; speedup 1.0000x reference)
//
#include <hip/hip_runtime.h>
#include <hip/hip_fp16.h>

typedef _Float16 half_t;
typedef __attribute__((ext_vector_type(8))) _Float16 half8;
typedef __attribute__((ext_vector_type(4))) float floatx4;

// ---------------------------------------------------------------------------
// NT GEMM: C[M x N] = A[M x K] * B[N x K]^T, fp32 accumulate via fp16 MFMA.
// BM=128, BN in {64,128}. 256 threads = 4 waves (2x2 wave grid).
// F16IN: 1 = operands are fp16; 0 = operands are fp32 (converted during
// staging: 2x float4 load -> 8x cvt -> half8 ds_write).
// EPI: 0 = fp16 store, 1 = fp16 transposed store (C[col*ldc+row]),
//      2 = f32 store * scale, 3 = f32 atomicAdd (split-K).
// blockIdx.z offsets A/B/C by sAz/sBz/sCz ELEMENTS.
template<int BN, int EPI, int F16IN>
__global__ __launch_bounds__(256) void gemm_nt(
    const void* __restrict__ Av, const void* __restrict__ Bv,
    void* __restrict__ Cout,
    int lda, int ldb, int ldc, int kIters,
    long sAz, long sBz, long sCz, float scale)
{
  constexpr int BM = 128;
  constexpr int WN = BN / 2;               // wave tile N (64 or 32)
  constexpr int AN = WN / 16;              // acc blocks in N (4 or 2)
  constexpr int RA = 2;                    // A chunks/thread
  constexpr int RB = (BN * 32 / 8) / 256;  // B chunks/thread (2 or 1)
  constexpr long ESZ = F16IN ? 2 : 4;      // input element bytes
  __shared__ __align__(16) half_t lA[BM * 32];
  __shared__ __align__(16) half_t lB[BN * 32];

  const int tid  = threadIdx.x;
  const int wave = tid >> 6, lane = tid & 63;
  const int wm = wave >> 1, wn = wave & 1;
  const int er = lane >> 4, ec = lane & 15;  // k-quad / row-in-16
  const long z = blockIdx.z;

  const char* Ab = (const char*)Av + ((long)blockIdx.x * BM * lda + z * sAz) * ESZ;
  const char* Bb = (const char*)Bv + ((long)blockIdx.y * BN * ldb + z * sBz) * ESZ;

  floatx4 acc[4][AN];
  #pragma unroll
  for (int i = 0; i < 4; i++)
    #pragma unroll
    for (int j = 0; j < AN; j++)
      acc[i][j] = (floatx4){0.f, 0.f, 0.f, 0.f};

  for (int ks = 0; ks < kIters; ++ks) {
    const char* Ak = Ab + (long)ks * 32 * ESZ;
    const char* Bk = Bb + (long)ks * 32 * ESZ;
    half8 ra[RA], rb[RB];
    #pragma unroll
    for (int r = 0; r < RA; r++) {
      int c = r * 256 + tid;               // chunk = (row<<2) | kpart
      const char* p = Ak + ((long)(c >> 2) * lda + (c & 3) * 8) * ESZ;
      if constexpr (F16IN) {
        ra[r] = *(const half8*)p;
      } else {
        float4 f0 = ((const float4*)p)[0], f1 = ((const float4*)p)[1];
        ra[r] = (half8){(_Float16)f0.x, (_Float16)f0.y, (_Float16)f0.z,
                        (_Float16)f0.w, (_Float16)f1.x, (_Float16)f1.y,
                        (_Float16)f1.z, (_Float16)f1.w};
      }
    }
    #pragma unroll
    for (int r = 0; r < RB; r++) {
      int c = r * 256 + tid;
      const char* p = Bk + ((long)(c >> 2) * ldb + (c & 3) * 8) * ESZ;
      if constexpr (F16IN) {
        rb[r] = *(const half8*)p;
      } else {
        float4 f0 = ((const float4*)p)[0], f1 = ((const float4*)p)[1];
        rb[r] = (half8){(_Float16)f0.x, (_Float16)f0.y, (_Float16)f0.z,
                        (_Float16)f0.w, (_Float16)f1.x, (_Float16)f1.y,
                        (_Float16)f1.z, (_Float16)f1.w};
      }
    }
    __syncthreads();   // WAR: prior iter's LDS reads done before overwrite
    #pragma unroll
    for (int r = 0; r < RA; r++) *(half8*)&lA[(r * 256 + tid) * 8] = ra[r];
    #pragma unroll
    for (int r = 0; r < RB; r++) *(half8*)&lB[(r * 256 + tid) * 8] = rb[r];
    __syncthreads();   // staged data visible

    half8 af[4], bfv[AN];
    #pragma unroll
    for (int i = 0; i < 4; i++)
      af[i] = *(const half8*)&lA[(wm * 64 + i * 16 + ec) * 32 + er * 8];
    #pragma unroll
    for (int j = 0; j < AN; j++)
      bfv[j] = *(const half8*)&lB[(wn * WN + j * 16 + ec) * 32 + er * 8];
    #pragma unroll
    for (int i = 0; i < 4; i++)
      #pragma unroll
      for (int j = 0; j < AN; j++)
        acc[i][j] = __builtin_amdgcn_mfma_f32_16x16x32_f16(
            af[i], bfv[j], acc[i][j], 0, 0, 0);
  }

  const long rowBase = (long)blockIdx.x * BM + wm * 64;
  const long colBase = (long)blockIdx.y * BN + wn * WN;
  #pragma unroll
  for (int i = 0; i < 4; i++)
    #pragma unroll
    for (int j = 0; j < AN; j++)
      #pragma unroll
      for (int r = 0; r < 4; r++) {
        long row = rowBase + i * 16 + er * 4 + r;   // C/D: row = quad*4+reg
        long col = colBase + j * 16 + ec;           // C/D: col = lane&15
        float v = acc[i][j][r];
        if constexpr (EPI == 0) {
          ((half_t*)Cout)[z * sCz + row * (long)ldc + col] = (_Float16)v;
        } else if constexpr (EPI == 1) {
          ((half_t*)Cout)[z * sCz + col * (long)ldc + row] = (_Float16)v;
        } else if constexpr (EPI == 2) {
          ((float*)Cout)[z * sCz + row * (long)ldc + col] = v * scale;
        } else {
          atomicAdd(&((float*)Cout)[z * sCz + row * (long)ldc + col], v);
        }
      }
}

// ---------------------------------------------------------------------------
// Row softmax over 2048 fp32 -> fp16, row stride ldP halves. Supports
// in-place (P == (half_t*)S, ldP = 4096): every thread's loads complete
// before barrier 1; all stores happen after barrier 2.
__global__ __launch_bounds__(256) void softmax_rows(
    const float* __restrict__ S, half_t* __restrict__ P, int ldP)
{
  const long row = blockIdx.x;
  const float4* sr = (const float4*)(S + row * 2048);
  const int t = threadIdx.x;
  const int wave = t >> 6, lane = t & 63;
  float4 v0 = sr[t * 2 + 0];
  float4 v1 = sr[t * 2 + 1];
  float m = fmaxf(fmaxf(fmaxf(v0.x, v0.y), fmaxf(v0.z, v0.w)),
                  fmaxf(fmaxf(v1.x, v1.y), fmaxf(v1.z, v1.w)));
  #pragma unroll
  for (int o = 32; o > 0; o >>= 1) m = fmaxf(m, __shfl_xor(m, o));
  __shared__ float rmax[4], rsum[4];
  if (lane == 0) rmax[wave] = m;
  __syncthreads();                       // barrier 1 (all row loads consumed)
  m = fmaxf(fmaxf(rmax[0], rmax[1]), fmaxf(rmax[2], rmax[3]));
  float e[8];
  e[0] = expf(v0.x - m); e[1] = expf(v0.y - m);
  e[2] = expf(v0.z - m); e[3] = expf(v0.w - m);
  e[4] = expf(v1.x - m); e[5] = expf(v1.y - m);
  e[6] = expf(v1.z - m); e[7] = expf(v1.w - m);
  float s = ((e[0] + e[1]) + (e[2] + e[3])) + ((e[4] + e[5]) + (e[6] + e[7]));
  #pragma unroll
  for (int o = 32; o > 0; o >>= 1) s += __shfl_xor(s, o);
  if (lane == 0) rsum[wave] = s;
  __syncthreads();                       // barrier 2
  float inv = 1.f / (rsum[0] + rsum[1] + rsum[2] + rsum[3]);
  half8 o8;
  #pragma unroll
  for (int k = 0; k < 8; k++) o8[k] = (_Float16)(e[k] * inv);
  ((half8*)(P + row * (long)ldP))[t] = o8;
}

// ---------------------------------------------------------------------------
// Per-head circuit constants through L variational layers.
// Emits A=<Z_q>, B=-<X_q>; data RY gives z_q = A cos(th) + B sin(th).
// Qubit q <-> amplitude-index bit mask 8>>q.
__global__ void quantum_prep(const float* __restrict__ qp,
                             float* __restrict__ qab, int L)
{
  int h = threadIdx.x;
  if (h >= 16) return;
  float st[16];
  #pragma unroll
  for (int i = 0; i < 16; i++) st[i] = 0.f;
  st[0] = 1.f;
  for (int l = 0; l < L; l++) {
    #pragma unroll
    for (int q = 0; q < 4; q++) {
      float th = qp[(h * L + l) * 4 + q];
      float c = cosf(0.5f * th), s = sinf(0.5f * th);
      int mq = 8 >> q;
      #pragma unroll
      for (int i = 0; i < 16; i++) {
        if ((i & mq) == 0) {
          float a0 = st[i], a1 = st[i | mq];
          st[i]      = c * a0 - s * a1;
          st[i | mq] = s * a0 + c * a1;
        }
      }
    }
    const int cm[4] = {8, 4, 2, 1};   // CNOT (0,1)(1,2)(2,3)(3,0)
    const int tm[4] = {4, 2, 1, 8};
    #pragma unroll
    for (int p = 0; p < 4; p++) {
      int mc = cm[p], mt = tm[p];
      #pragma unroll
      for (int i = 0; i < 16; i++) {
        if ((i & mc) != 0 && (i & mt) == 0) {
          float tv = st[i]; st[i] = st[i | mt]; st[i | mt] = tv;
        }
      }
    }
  }
  #pragma unroll
  for (int q = 0; q < 4; q++) {
    int mq = 8 >> q;
    float zc = 0.f, xc = 0.f;
    #pragma unroll
    for (int i = 0; i < 16; i++) {
      float p2 = st[i] * st[i];
      zc += ((i & mq) == 0) ? p2 : -p2;
      if ((i & mq) == 0) xc += st[i] * st[i | mq];
    }
    qab[(h * 4 + q) * 2 + 0] = zc;
    qab[(h * 4 + q) * 2 + 1] = -2.f * xc;
  }
}

// z = A[c]*cos(theta) + B[c]*sin(theta) over O4[8192][64].
__global__ __launch_bounds__(256) void quantum_z(
    const float* __restrict__ O4, const float* __restrict__ qab,
    half_t* __restrict__ Z4)
{
  int idx = blockIdx.x * 256 + threadIdx.x;
  int c = idx & 63;
  float th = O4[idx];
  Z4[idx] = (_Float16)(qab[2 * c] * cosf(th) + qab[2 * c + 1] * sinf(th));
}

// Gather 64 used rows of Wv (fp32 out): Wvs[c][e] = Wv[(c>>2)*64 + (c&3)][e]
__global__ __launch_bounds__(256) void pack_wv(const float* __restrict__ Wv,
                                               float* __restrict__ Wvs)
{
  int idx = blockIdx.x * 256 + threadIdx.x;     // 64*1024
  int c = idx >> 10, e = idx & 1023;
  Wvs[idx] = Wv[(long)(((c >> 2) << 6) | (c & 3)) * 1024 + e];
}

// Gather 64 used cols of Wo (fp16 out): Wos[e][c] = Wo[e][(c>>2)*64 + (c&3)]
__global__ __launch_bounds__(256) void pack_wo(const float* __restrict__ Wo,
                                               half_t* __restrict__ Wos)
{
  int idx = blockIdx.x * 256 + threadIdx.x;     // 1024*64
  int e = idx >> 6, c = idx & 63;
  Wos[idx] = (_Float16)Wo[(long)e * 1024 + (((c >> 2) << 6) | (c & 3))];
}

// ---------------------------------------------------------------------------
extern "C" void kernel_launch(void* const* d_in, const int* in_sizes, int n_in,
                              void* d_out, int out_size, void* d_ws, size_t ws_size,
                              hipStream_t stream)
{
  const float* x  = (const float*)d_in[0];
  const float* Wq = (const float*)d_in[1];
  const float* Wk = (const float*)d_in[2];
  const float* Wv = (const float*)d_in[3];
  const float* Wo = (const float*)d_in[4];
  const float* qp = (const float*)d_in[5];
  const int L = in_sizes[5] / 64;     // H*NQ = 64
  float* out = (float*)d_out;

  // B=4, T=2048, E=1024, H=16, hd=64, NQ=4; 8192 tokens.
  char* w = (char*)d_ws;
  size_t off = 0;
  auto alloc = [&](size_t bytes) -> void* {
    void* p = w + off;
    off = (off + bytes + 255) & ~(size_t)255;
    return p;
  };
  float* qab  = (float*)alloc(64 * 2 * sizeof(float));
  float* Wvs  = (float*)alloc((size_t)64 * 1024 * 4);
  half_t* Wos = (half_t*)alloc((size_t)1024 * 64 * 2);
  half_t* V4t = (half_t*)alloc((size_t)64 * 8192 * 2);   // [chan][token]
  float* O4   = (float*)alloc((size_t)8192 * 64 * 4);
  half_t* Z4  = (half_t*)alloc((size_t)8192 * 64 * 2);

  // Q and K projections (fp16, 16.78 MB each) live in d_out (33.55 MB fp32):
  // both fully consumed before the final GEMM overwrites d_out.
  half_t* Kb = (half_t*)d_out;
  half_t* Qb = (half_t*)d_out + (size_t)8192 * 1024;

  // Score-chunk rows R from remaining workspace (S reused per chunk;
  // softmax stores fp16 P in-place over S, row stride 4096 halves).
  int R = 2048;
  if (ws_size < off + (size_t)2048 * 2048 * 4 + 256) R = 512;
  if (ws_size < off + (size_t)512  * 2048 * 4 + 256) R = 128;
  float* S = (float*)alloc((size_t)R * 2048 * 4);

  quantum_prep<<<dim3(1), dim3(64), 0, stream>>>(qp, qab, L);
  pack_wv<<<dim3(256), dim3(256), 0, stream>>>(Wv, Wvs);
  pack_wo<<<dim3(256), dim3(256), 0, stream>>>(Wo, Wos);
  hipMemsetAsync(O4, 0, (size_t)8192 * 64 * 4, stream);

  // Q = x Wq^T, K = x Wk^T  (8192x1024, K=1024), fp32 in -> fp16 out
  gemm_nt<128, 0, 0><<<dim3(64, 8, 1), 256, 0, stream>>>(
      x, Wq, Qb, 1024, 1024, 1024, 32, 0, 0, 0, 1.f);
  gemm_nt<128, 0, 0><<<dim3(64, 8, 1), 256, 0, stream>>>(
      x, Wk, Kb, 1024, 1024, 1024, 32, 0, 0, 0, 1.f);
  // V4t[c][n] = sum_e x[n][e] Wvs[c][e]  (transposed store, ldc=8192)
  gemm_nt<64, 1, 0><<<dim3(64, 1, 1), 256, 0, stream>>>(
      x, Wvs, V4t, 1024, 1024, 8192, 32, 0, 0, 0, 1.f);

  // Attention in chunks of R query rows (chunks never span batches).
  const int nC = 8192 / R;
  for (int c = 0; c < nC; c++) {
    const int row0 = c * R;
    const int b = row0 >> 11;            // batch of this chunk
    // S = (Q_chunk K_b^T) / 32  (fp32 store)
    gemm_nt<128, 2, 1><<<dim3(R / 128, 16, 1), 256, 0, stream>>>(
        Qb + (long)row0 * 1024, Kb + (long)b * 2048 * 1024, S,
        1024, 1024, 2048, 32, 0, 0, 0, 0.03125f);
    // softmax -> fp16 P in-place
    softmax_rows<<<dim3(R), dim3(256), 0, stream>>>(S, (half_t*)S, 4096);
    // O4_chunk += P * V4_b  (split-K=8 over 2048 keys, f32 atomics)
    gemm_nt<64, 3, 1><<<dim3(R / 128, 1, 8), 256, 0, stream>>>(
        (const half_t*)S, V4t + (long)b * 2048, O4 + (long)row0 * 64,
        4096, 8192, 64, 8, 256, 256, 0, 1.f);
  }

  // quantum elementwise + final out = Z4 * Wos^T (K=64, fp32 store)
  quantum_z<<<dim3(2048), dim3(256), 0, stream>>>(O4, qab, Z4);
  gemm_nt<128, 2, 1><<<dim3(64, 8, 1), 256, 0, stream>>>(
      Z4, Wos, out, 64, 64, 1024, 2, 0, 0, 0, 1.f);
}

// Round 4
// 312.700 us; speedup vs baseline: 1.2523x; 1.2523x over previous
//
#include <hip/hip_runtime.h>
#include <hip/hip_fp16.h>

typedef _Float16 half_t;
typedef __attribute__((ext_vector_type(8))) _Float16 half8;
typedef __attribute__((ext_vector_type(4))) float floatx4;

// async global->LDS, 16B/lane. LDS base must be wave-uniform; HW adds lane*16.
__device__ __forceinline__ void async_copy16(const void* src, void* dst_lds) {
  __builtin_amdgcn_global_load_lds(
      (__attribute__((address_space(1))) void*)src,
      (__attribute__((address_space(3))) void*)dst_lds, 16, 0, 0);
}

// ---------------------------------------------------------------------------
// NT GEMM: C[M x N] = A[M x K] * B[N x K]^T, fp16 in, fp32 accum (MFMA
// 16x16x32). BM=128, BN in {64,128}. 256 thr = 4 waves (2x2).
// Staging: global_load_lds 16B with XOR swizzle (slot = kq ^ ((row>>1)&3))
// so fragment ds_read_b128 is 2-way-conflict-free.
// EPI: 0 = fp16 store, 2 = f32 store*scale, 3 = f32 atomicAdd,
//      4 = f32 atomicAdd transposed (C[col*ldc+row]).
// z decomposition: z2 = z>>zShift, z1 = z & ((1<<zShift)-1); offsets
// z1*s?z1 + z2*s?z2 (elements).
template<int BN, int EPI>
__global__ __launch_bounds__(256) void gemm_nt(
    const half_t* __restrict__ A, const half_t* __restrict__ B,
    void* __restrict__ Cout,
    int lda, int ldb, int ldc, int kIters, int zShift,
    long sAz1, long sBz1, long sCz1,
    long sAz2, long sBz2, long sCz2, float scale)
{
  constexpr int BM = 128;
  constexpr int WN = BN / 2;          // wave tile N (64 or 32)
  constexpr int AN = WN / 16;         // acc blocks in N (4 or 2)
  constexpr int RA = BM * 4 / 256;    // A 16B-chunks per thread (2)
  constexpr int RB = BN * 4 / 256;    // B chunks per thread (2 or 1)
  __shared__ __align__(16) half_t lA[BM * 32];
  __shared__ __align__(16) half_t lB[BN * 32];

  const int tid  = threadIdx.x;
  const int wave = tid >> 6, lane = tid & 63;
  const int wm = wave >> 1, wn = wave & 1;
  const int er = lane >> 4, ec = lane & 15;   // k-quad / row-in-16
  const int sw = (ec >> 1) & 3;               // read-side swizzle

  const long z = blockIdx.z;
  const long z2 = z >> zShift;
  const long z1 = z - (z2 << zShift);
  const half_t* Ab = A + (long)blockIdx.x * BM * lda + z1 * sAz1 + z2 * sAz2;
  const half_t* Bb = B + (long)blockIdx.y * BN * ldb + z1 * sBz1 + z2 * sBz2;
  const long cz = z1 * sCz1 + z2 * sCz2;

  floatx4 acc[4][AN];
  #pragma unroll
  for (int i = 0; i < 4; i++)
    #pragma unroll
    for (int j = 0; j < AN; j++)
      acc[i][j] = (floatx4){0.f, 0.f, 0.f, 0.f};

  for (int ks = 0; ks < kIters; ++ks) {
    const half_t* Ak = Ab + ks * 32;
    const half_t* Bk = Bb + ks * 32;
    #pragma unroll
    for (int r = 0; r < RA; r++) {
      int c = r * 256 + tid;                  // LDS 16B slot index
      int row = c >> 2;
      int kq = (c & 3) ^ ((row >> 1) & 3);    // swizzled source k-chunk
      async_copy16(Ak + (long)row * lda + kq * 8,
                   &lA[(r * 256 + wave * 64) * 8]);
    }
    #pragma unroll
    for (int r = 0; r < RB; r++) {
      int c = r * 256 + tid;
      int row = c >> 2;
      int kq = (c & 3) ^ ((row >> 1) & 3);
      async_copy16(Bk + (long)row * ldb + kq * 8,
                   &lB[(r * 256 + wave * 64) * 8]);
    }
    __syncthreads();   // drains vmcnt: LDS staged

    half8 af[4], bfv[AN];
    #pragma unroll
    for (int i = 0; i < 4; i++)
      af[i] = *(const half8*)&lA[(wm * 64 + i * 16 + ec) * 32 + ((er ^ sw) * 8)];
    #pragma unroll
    for (int j = 0; j < AN; j++)
      bfv[j] = *(const half8*)&lB[(wn * WN + j * 16 + ec) * 32 + ((er ^ sw) * 8)];
    #pragma unroll
    for (int i = 0; i < 4; i++)
      #pragma unroll
      for (int j = 0; j < AN; j++)
        acc[i][j] = __builtin_amdgcn_mfma_f32_16x16x32_f16(
            af[i], bfv[j], acc[i][j], 0, 0, 0);
    __syncthreads();   // WAR before next stage
  }

  const long rowBase = (long)blockIdx.x * BM + wm * 64;
  const long colBase = (long)blockIdx.y * BN + wn * WN;
  #pragma unroll
  for (int i = 0; i < 4; i++)
    #pragma unroll
    for (int j = 0; j < AN; j++)
      #pragma unroll
      for (int r = 0; r < 4; r++) {
        long row = rowBase + i * 16 + er * 4 + r;   // C/D: row = quad*4+reg
        long col = colBase + j * 16 + ec;           // C/D: col = lane&15
        float v = acc[i][j][r];
        if constexpr (EPI == 0) {
          ((half_t*)Cout)[cz + row * (long)ldc + col] = (_Float16)v;
        } else if constexpr (EPI == 2) {
          ((float*)Cout)[cz + row * (long)ldc + col] = v * scale;
        } else if constexpr (EPI == 3) {
          atomicAdd(&((float*)Cout)[cz + row * (long)ldc + col], v);
        } else {
          atomicAdd(&((float*)Cout)[cz + col * (long)ldc + row], v);
        }
      }
}

// ---------------------------------------------------------------------------
// Row softmax over 2048 fp32 -> fp16 at row stride ldP halves (in-place OK:
// all loads complete before barrier 1, stores after barrier 2).
__global__ __launch_bounds__(256) void softmax_rows(
    const float* __restrict__ S, half_t* __restrict__ P, int ldP)
{
  const long row = blockIdx.x;
  const float4* sr = (const float4*)(S + row * 2048);
  const int t = threadIdx.x;
  const int wave = t >> 6, lane = t & 63;
  float4 v0 = sr[t * 2 + 0];
  float4 v1 = sr[t * 2 + 1];
  float m = fmaxf(fmaxf(fmaxf(v0.x, v0.y), fmaxf(v0.z, v0.w)),
                  fmaxf(fmaxf(v1.x, v1.y), fmaxf(v1.z, v1.w)));
  #pragma unroll
  for (int o = 32; o > 0; o >>= 1) m = fmaxf(m, __shfl_xor(m, o));
  __shared__ float rmax[4], rsum[4];
  if (lane == 0) rmax[wave] = m;
  __syncthreads();
  m = fmaxf(fmaxf(rmax[0], rmax[1]), fmaxf(rmax[2], rmax[3]));
  float e[8];
  e[0] = expf(v0.x - m); e[1] = expf(v0.y - m);
  e[2] = expf(v0.z - m); e[3] = expf(v0.w - m);
  e[4] = expf(v1.x - m); e[5] = expf(v1.y - m);
  e[6] = expf(v1.z - m); e[7] = expf(v1.w - m);
  float s = ((e[0] + e[1]) + (e[2] + e[3])) + ((e[4] + e[5]) + (e[6] + e[7]));
  #pragma unroll
  for (int o = 32; o > 0; o >>= 1) s += __shfl_xor(s, o);
  if (lane == 0) rsum[wave] = s;
  __syncthreads();
  float inv = 1.f / (rsum[0] + rsum[1] + rsum[2] + rsum[3]);
  half8 o8;
  #pragma unroll
  for (int k = 0; k < 8; k++) o8[k] = (_Float16)(e[k] * inv);
  ((half8*)(P + row * (long)ldP))[t] = o8;
}

// ---------------------------------------------------------------------------
// Per-head circuit constants through L variational layers.
// A=<Z_q>, B=-<X_q>; data RY gives z_q = A cos(th) + B sin(th).
__global__ void quantum_prep(const float* __restrict__ qp,
                             float* __restrict__ qab, int L)
{
  int h = threadIdx.x;
  if (h >= 16) return;
  float st[16];
  #pragma unroll
  for (int i = 0; i < 16; i++) st[i] = 0.f;
  st[0] = 1.f;
  for (int l = 0; l < L; l++) {
    #pragma unroll
    for (int q = 0; q < 4; q++) {
      float th = qp[(h * L + l) * 4 + q];
      float c = cosf(0.5f * th), s = sinf(0.5f * th);
      int mq = 8 >> q;
      #pragma unroll
      for (int i = 0; i < 16; i++) {
        if ((i & mq) == 0) {
          float a0 = st[i], a1 = st[i | mq];
          st[i]      = c * a0 - s * a1;
          st[i | mq] = s * a0 + c * a1;
        }
      }
    }
    const int cm[4] = {8, 4, 2, 1};   // CNOT (0,1)(1,2)(2,3)(3,0)
    const int tm[4] = {4, 2, 1, 8};
    #pragma unroll
    for (int p = 0; p < 4; p++) {
      int mc = cm[p], mt = tm[p];
      #pragma unroll
      for (int i = 0; i < 16; i++) {
        if ((i & mc) != 0 && (i & mt) == 0) {
          float tv = st[i]; st[i] = st[i | mt]; st[i | mt] = tv;
        }
      }
    }
  }
  #pragma unroll
  for (int q = 0; q < 4; q++) {
    int mq = 8 >> q;
    float zc = 0.f, xc = 0.f;
    #pragma unroll
    for (int i = 0; i < 16; i++) {
      float p2 = st[i] * st[i];
      zc += ((i & mq) == 0) ? p2 : -p2;
      if ((i & mq) == 0) xc += st[i] * st[i | mq];
    }
    qab[(h * 4 + q) * 2 + 0] = zc;
    qab[(h * 4 + q) * 2 + 1] = -2.f * xc;
  }
}

// z = A[c]*cos(theta) + B[c]*sin(theta) over O4[8192][64].
__global__ __launch_bounds__(256) void quantum_z(
    const float* __restrict__ O4, const float* __restrict__ qab,
    half_t* __restrict__ Z4)
{
  int idx = blockIdx.x * 256 + threadIdx.x;
  int c = idx & 63;
  float th = O4[idx];
  Z4[idx] = (_Float16)(qab[2 * c] * cosf(th) + qab[2 * c + 1] * sinf(th));
}

// fp32 -> fp16, 8 elements/thread
__global__ __launch_bounds__(256) void cvt_f2h(const float* __restrict__ in,
                                               half_t* __restrict__ outp, long n)
{
  long i = ((long)blockIdx.x * 256 + threadIdx.x) * 8;
  if (i >= n) return;
  float4 a = *(const float4*)(in + i);
  float4 b = *(const float4*)(in + i + 4);
  half8 h = {(_Float16)a.x, (_Float16)a.y, (_Float16)a.z, (_Float16)a.w,
             (_Float16)b.x, (_Float16)b.y, (_Float16)b.z, (_Float16)b.w};
  *(half8*)(outp + i) = h;
}

// Wqk[r][e]: r<1024 -> Wq row r, else Wk row r-1024 (fp16). 8 elts/thread.
__global__ __launch_bounds__(256) void pack_wqk(const float* __restrict__ Wq,
                                                const float* __restrict__ Wk,
                                                half_t* __restrict__ outp)
{
  long i = ((long)blockIdx.x * 256 + threadIdx.x) * 8;   // over 2048*1024
  int r = (int)(i >> 10);
  int e = (int)(i & 1023);
  const float* src = (r < 1024 ? Wq + (long)r * 1024
                               : Wk + (long)(r - 1024) * 1024) + e;
  float4 a = *(const float4*)src;
  float4 b = *(const float4*)(src + 4);
  half8 h = {(_Float16)a.x, (_Float16)a.y, (_Float16)a.z, (_Float16)a.w,
             (_Float16)b.x, (_Float16)b.y, (_Float16)b.z, (_Float16)b.w};
  *(half8*)(outp + i) = h;
}

// Wv4[c][e] = Wv[(c>>2)*64 + (c&3)][e] fp16, 64x1024, 8 elts/thread.
__global__ __launch_bounds__(256) void pack_wv4(const float* __restrict__ Wv,
                                                half_t* __restrict__ outp)
{
  long i = ((long)blockIdx.x * 256 + threadIdx.x) * 8;   // over 64*1024
  int c = (int)(i >> 10);
  int e = (int)(i & 1023);
  const float* src = Wv + (long)(((c >> 2) << 6) | (c & 3)) * 1024 + e;
  float4 a = *(const float4*)src;
  float4 b = *(const float4*)(src + 4);
  half8 h = {(_Float16)a.x, (_Float16)a.y, (_Float16)a.z, (_Float16)a.w,
             (_Float16)b.x, (_Float16)b.y, (_Float16)b.z, (_Float16)b.w};
  *(half8*)(outp + i) = h;
}

// Wos[e][c] = Wo[e][(c>>2)*64 + (c&3)] fp16.
__global__ __launch_bounds__(256) void pack_wo(const float* __restrict__ Wo,
                                               half_t* __restrict__ outp)
{
  int idx = blockIdx.x * 256 + threadIdx.x;   // 1024*64
  int e = idx >> 6, c = idx & 63;
  outp[idx] = (_Float16)Wo[(long)e * 1024 + (((c >> 2) << 6) | (c & 3))];
}

// ---------------------------------------------------------------------------
extern "C" void kernel_launch(void* const* d_in, const int* in_sizes, int n_in,
                              void* d_out, int out_size, void* d_ws, size_t ws_size,
                              hipStream_t stream)
{
  const float* x  = (const float*)d_in[0];
  const float* Wq = (const float*)d_in[1];
  const float* Wk = (const float*)d_in[2];
  const float* Wv = (const float*)d_in[3];
  const float* Wo = (const float*)d_in[4];
  const float* qp = (const float*)d_in[5];
  const int L = in_sizes[5] / 64;     // H*NQ = 64
  float* out = (float*)d_out;

  // B=4, T=2048, E=1024, H=16, hd=64, NQ=4; 8192 tokens.
  char* w = (char*)d_ws;
  size_t off = 0;
  auto alloc = [&](size_t bytes) -> void* {
    void* p = w + off;
    off = (off + bytes + 255) & ~(size_t)255;
    return p;
  };
  float*  qab  = (float*)alloc(512);
  half_t* xh   = (half_t*)alloc((size_t)8192 * 1024 * 2);
  half_t* Wqk  = (half_t*)alloc((size_t)2048 * 1024 * 2);
  half_t* Wv4  = (half_t*)alloc((size_t)64 * 1024 * 2);
  half_t* Wos  = (half_t*)alloc((size_t)1024 * 64 * 2);
  float*  V4tf = (float*)alloc((size_t)64 * 8192 * 4);
  half_t* V4th = (half_t*)alloc((size_t)64 * 8192 * 2);
  float*  O4   = (float*)alloc((size_t)8192 * 64 * 4);
  half_t* Z4   = (half_t*)alloc((size_t)8192 * 64 * 2);

  // QK projections (fp16, [8192][2048]: cols 0..1023 = Q, 1024..2047 = K)
  // live in d_out (exactly 33.55 MB); fully consumed before final GEMM.
  half_t* QKb = (half_t*)d_out;

  // S tier: 0 = all 4 batches (67 MB), 1 = per-batch (16.8 MB), 2 = 512-row.
  int tier;
  if      (ws_size >= off + (size_t)8192 * 2048 * 4 + 256) tier = 0;
  else if (ws_size >= off + (size_t)2048 * 2048 * 4 + 256) tier = 1;
  else                                                     tier = 2;
  const size_t Sn = (tier == 0) ? (size_t)8192 * 2048
                  : (tier == 1) ? (size_t)2048 * 2048 : (size_t)512 * 2048;
  float* S = (float*)alloc(Sn * 4);

  // --- prep ---
  quantum_prep<<<dim3(1), dim3(64), 0, stream>>>(qp, qab, L);
  cvt_f2h<<<dim3(4096), dim3(256), 0, stream>>>(x, xh, (long)8192 * 1024);
  pack_wqk<<<dim3(1024), dim3(256), 0, stream>>>(Wq, Wk, Wqk);
  pack_wv4<<<dim3(32), dim3(256), 0, stream>>>(Wv, Wv4);
  pack_wo<<<dim3(256), dim3(256), 0, stream>>>(Wo, Wos);
  hipMemsetAsync(V4tf, 0, (size_t)64 * 8192 * 4, stream);
  hipMemsetAsync(O4, 0, (size_t)8192 * 64 * 4, stream);

  // --- QK projection: [Q|K] = xh @ Wqk^T  (8192 x 2048, K=1024) ---
  gemm_nt<128, 0><<<dim3(64, 16, 1), 256, 0, stream>>>(
      xh, Wqk, QKb, 1024, 1024, 2048, 32, 0,
      0, 0, 0, 0, 0, 0, 1.f);
  // --- V4 projection, split-K=4, transposed atomics into V4tf[64][8192] ---
  gemm_nt<64, 4><<<dim3(64, 1, 4), 256, 0, stream>>>(
      xh, Wv4, V4tf, 1024, 1024, 8192, 8, 0,
      0, 0, 0, 256, 256, 0, 1.f);
  cvt_f2h<<<dim3(256), dim3(256), 0, stream>>>(V4tf, V4th, (long)64 * 8192);

  if (tier == 0) {
    // scores all batches: grid (16,16,4), z = batch
    gemm_nt<128, 2><<<dim3(16, 16, 4), 256, 0, stream>>>(
        QKb, QKb + 1024, S, 2048, 2048, 2048, 32, 0,
        0, 0, 0, (long)2048 * 2048, (long)2048 * 2048, (long)2048 * 2048,
        0.03125f);
    softmax_rows<<<dim3(8192), dim3(256), 0, stream>>>(S, (half_t*)S, 4096);
    // PV: grid (16,1,32), z = batch*8 + split (zShift=3)
    gemm_nt<64, 3><<<dim3(16, 1, 32), 256, 0, stream>>>(
        (const half_t*)S, V4th, O4, 4096, 8192, 64, 8, 3,
        256, 256, 0, (long)2048 * 4096, 2048, (long)2048 * 64, 1.f);
  } else {
    const int R = (tier == 1) ? 2048 : 512;
    for (int row0 = 0; row0 < 8192; row0 += R) {
      const int b = row0 >> 11;
      gemm_nt<128, 2><<<dim3(R / 128, 16, 1), 256, 0, stream>>>(
          QKb + (long)row0 * 2048, QKb + 1024 + (long)b * 2048 * 2048, S,
          2048, 2048, 2048, 32, 0, 0, 0, 0, 0, 0, 0, 0.03125f);
      softmax_rows<<<dim3(R), dim3(256), 0, stream>>>(S, (half_t*)S, 4096);
      gemm_nt<64, 3><<<dim3(R / 128, 1, 8), 256, 0, stream>>>(
          (const half_t*)S, V4th + (long)b * 2048, O4 + (long)row0 * 64,
          4096, 8192, 64, 8, 3, 256, 256, 0, 0, 0, 0, 1.f);
    }
  }

  // quantum elementwise + final out = Z4 @ Wos^T (K=64, fp32 store)
  quantum_z<<<dim3(2048), dim3(256), 0, stream>>>(O4, qab, Z4);
  gemm_nt<128, 2><<<dim3(64, 8, 1), 256, 0, stream>>>(
      Z4, Wos, out, 64, 64, 1024, 2, 0, 0, 0, 0, 0, 0, 0, 1.f);
}

// Round 5
// 281.119 us; speedup vs baseline: 1.3930x; 1.1123x over previous
//
#include <hip/hip_runtime.h>
#include <hip/hip_fp16.h>

typedef _Float16 half_t;
typedef __attribute__((ext_vector_type(8))) _Float16 half8;
typedef __attribute__((ext_vector_type(4))) float floatx4;

// async global->LDS, 16B/lane. LDS base must be wave-uniform; HW adds lane*16.
__device__ __forceinline__ void async_copy16(const void* src, void* dst_lds) {
  __builtin_amdgcn_global_load_lds(
      (__attribute__((address_space(1))) void*)src,
      (__attribute__((address_space(3))) void*)dst_lds, 16, 0, 0);
}

// ---------------------------------------------------------------------------
// NT GEMM: C[M x N] = A[M x K] * B[N x K]^T, fp16 in, fp32 accum
// (mfma 16x16x32). BM=128, BN in {64,128}. 256 thr = 4 waves (2x2).
// BK=64: 32 MFMAs between barrier pairs (halves barrier-drain stalls).
// LDS row = 64 halves = 8 x 16B chunks; physical chunk = logical ^ (row&7)
// -> ds_read_b128 fragments are 2-way-bank-aliased (free), DMA coalesced.
// EPI: 0 = fp16 store*scale, 2 = f32 store*scale, 3 = f32 atomicAdd,
//      4 = f32 atomicAdd transposed (C[col*ldc+row]).
// z: z2 = z>>zShift, z1 = z & mask; offsets z1*s?z1 + z2*s?z2 (elements).
template<int BN, int EPI>
__global__ __launch_bounds__(256) void gemm_nt(
    const half_t* __restrict__ A, const half_t* __restrict__ B,
    void* __restrict__ Cout,
    int lda, int ldb, int ldc, int kIters, int zShift,
    long sAz1, long sBz1, long sCz1,
    long sAz2, long sBz2, long sCz2, float scale)
{
  constexpr int BM = 128;
  constexpr int WN = BN / 2;          // wave tile N (64 or 32)
  constexpr int AN = WN / 16;         // acc blocks in N (4 or 2)
  constexpr int RA = BM * 8 / 256;    // A 16B-chunks per thread (4)
  constexpr int RB = BN * 8 / 256;    // B chunks per thread (4 or 2)
  __shared__ __align__(16) half_t lA[BM * 64];
  __shared__ __align__(16) half_t lB[BN * 64];

  const int tid  = threadIdx.x;
  const int wave = tid >> 6, lane = tid & 63;
  const int wm = wave >> 1, wn = wave & 1;
  const int er = lane >> 4, ec = lane & 15;   // k-quad / row-in-16
  const int sw = ec & 7;                      // read-side swizzle (row&7)

  const long z = blockIdx.z;
  const long z2 = z >> zShift;
  const long z1 = z - (z2 << zShift);
  const half_t* Ab = A + (long)blockIdx.x * BM * lda + z1 * sAz1 + z2 * sAz2;
  const half_t* Bb = B + (long)blockIdx.y * BN * ldb + z1 * sBz1 + z2 * sBz2;
  const long cz = z1 * sCz1 + z2 * sCz2;

  floatx4 acc[4][AN];
  #pragma unroll
  for (int i = 0; i < 4; i++)
    #pragma unroll
    for (int j = 0; j < AN; j++)
      acc[i][j] = (floatx4){0.f, 0.f, 0.f, 0.f};

  for (int ks = 0; ks < kIters; ++ks) {
    const half_t* Ak = Ab + ks * 64;
    const half_t* Bk = Bb + ks * 64;
    #pragma unroll
    for (int r = 0; r < RA; r++) {
      int s = r * 256 + tid;                  // LDS 16B slot
      int row = s >> 3;
      int kq = (s & 7) ^ (row & 7);           // swizzled source chunk
      async_copy16(Ak + (long)row * lda + kq * 8,
                   &lA[(r * 256 + wave * 64) * 8]);
    }
    #pragma unroll
    for (int r = 0; r < RB; r++) {
      int s = r * 256 + tid;
      int row = s >> 3;
      int kq = (s & 7) ^ (row & 7);
      async_copy16(Bk + (long)row * ldb + kq * 8,
                   &lB[(r * 256 + wave * 64) * 8]);
    }
    __syncthreads();   // drains vmcnt: LDS staged

    #pragma unroll
    for (int h = 0; h < 2; h++) {             // two 32-k sub-steps
      half8 af[4], bfv[AN];
      #pragma unroll
      for (int i = 0; i < 4; i++) {
        int row = wm * 64 + i * 16 + ec;
        af[i] = *(const half8*)&lA[row * 64 + (((h * 4 + er) ^ sw) * 8)];
      }
      #pragma unroll
      for (int j = 0; j < AN; j++) {
        int row = wn * WN + j * 16 + ec;
        bfv[j] = *(const half8*)&lB[row * 64 + (((h * 4 + er) ^ sw) * 8)];
      }
      #pragma unroll
      for (int i = 0; i < 4; i++)
        #pragma unroll
        for (int j = 0; j < AN; j++)
          acc[i][j] = __builtin_amdgcn_mfma_f32_16x16x32_f16(
              af[i], bfv[j], acc[i][j], 0, 0, 0);
    }
    __syncthreads();   // WAR before next stage
  }

  const long rowBase = (long)blockIdx.x * BM + wm * 64;
  const long colBase = (long)blockIdx.y * BN + wn * WN;
  #pragma unroll
  for (int i = 0; i < 4; i++)
    #pragma unroll
    for (int j = 0; j < AN; j++)
      #pragma unroll
      for (int r = 0; r < 4; r++) {
        long row = rowBase + i * 16 + er * 4 + r;   // C/D: row = quad*4+reg
        long col = colBase + j * 16 + ec;           // C/D: col = lane&15
        float v = acc[i][j][r];
        if constexpr (EPI == 0) {
          ((half_t*)Cout)[cz + row * (long)ldc + col] = (_Float16)(v * scale);
        } else if constexpr (EPI == 2) {
          ((float*)Cout)[cz + row * (long)ldc + col] = v * scale;
        } else if constexpr (EPI == 3) {
          atomicAdd(&((float*)Cout)[cz + row * (long)ldc + col], v);
        } else {
          atomicAdd(&((float*)Cout)[cz + col * (long)ldc + row], v);
        }
      }
}

// ---------------------------------------------------------------------------
// In-place row softmax over 2048 fp16 (row stride ld halves). All loads
// complete before barrier 1; all stores after barrier 2.
__global__ __launch_bounds__(256) void softmax_rows(half_t* __restrict__ S,
                                                    int ld)
{
  const long row = blockIdx.x;
  half8* sp = (half8*)(S + row * (long)ld);
  const int t = threadIdx.x;
  const int wave = t >> 6, lane = t & 63;
  half8 hv = sp[t];
  float e[8];
  #pragma unroll
  for (int k = 0; k < 8; k++) e[k] = (float)hv[k];
  float m = e[0];
  #pragma unroll
  for (int k = 1; k < 8; k++) m = fmaxf(m, e[k]);
  #pragma unroll
  for (int o = 32; o > 0; o >>= 1) m = fmaxf(m, __shfl_xor(m, o));
  __shared__ float rmax[4], rsum[4];
  if (lane == 0) rmax[wave] = m;
  __syncthreads();
  m = fmaxf(fmaxf(rmax[0], rmax[1]), fmaxf(rmax[2], rmax[3]));
  float s = 0.f;
  #pragma unroll
  for (int k = 0; k < 8; k++) { e[k] = expf(e[k] - m); s += e[k]; }
  #pragma unroll
  for (int o = 32; o > 0; o >>= 1) s += __shfl_xor(s, o);
  if (lane == 0) rsum[wave] = s;
  __syncthreads();
  float inv = 1.f / (rsum[0] + rsum[1] + rsum[2] + rsum[3]);
  half8 o8;
  #pragma unroll
  for (int k = 0; k < 8; k++) o8[k] = (_Float16)(e[k] * inv);
  sp[t] = o8;
}

// ---------------------------------------------------------------------------
// Per-head circuit constants through L variational layers.
// A=<Z_q>, B=-<X_q>; data RY gives z_q = A cos(th) + B sin(th).
__global__ void quantum_prep(const float* __restrict__ qp,
                             float* __restrict__ qab, int L)
{
  int h = threadIdx.x;
  if (h >= 16) return;
  float st[16];
  #pragma unroll
  for (int i = 0; i < 16; i++) st[i] = 0.f;
  st[0] = 1.f;
  for (int l = 0; l < L; l++) {
    #pragma unroll
    for (int q = 0; q < 4; q++) {
      float th = qp[(h * L + l) * 4 + q];
      float c = cosf(0.5f * th), s = sinf(0.5f * th);
      int mq = 8 >> q;
      #pragma unroll
      for (int i = 0; i < 16; i++) {
        if ((i & mq) == 0) {
          float a0 = st[i], a1 = st[i | mq];
          st[i]      = c * a0 - s * a1;
          st[i | mq] = s * a0 + c * a1;
        }
      }
    }
    const int cm[4] = {8, 4, 2, 1};   // CNOT (0,1)(1,2)(2,3)(3,0)
    const int tm[4] = {4, 2, 1, 8};
    #pragma unroll
    for (int p = 0; p < 4; p++) {
      int mc = cm[p], mt = tm[p];
      #pragma unroll
      for (int i = 0; i < 16; i++) {
        if ((i & mc) != 0 && (i & mt) == 0) {
          float tv = st[i]; st[i] = st[i | mt]; st[i | mt] = tv;
        }
      }
    }
  }
  #pragma unroll
  for (int q = 0; q < 4; q++) {
    int mq = 8 >> q;
    float zc = 0.f, xc = 0.f;
    #pragma unroll
    for (int i = 0; i < 16; i++) {
      float p2 = st[i] * st[i];
      zc += ((i & mq) == 0) ? p2 : -p2;
      if ((i & mq) == 0) xc += st[i] * st[i | mq];
    }
    qab[(h * 4 + q) * 2 + 0] = zc;
    qab[(h * 4 + q) * 2 + 1] = -2.f * xc;
  }
}

// z = A[c]*cos(theta) + B[c]*sin(theta) over O4[8192][64].
__global__ __launch_bounds__(256) void quantum_z(
    const float* __restrict__ O4, const float* __restrict__ qab,
    half_t* __restrict__ Z4)
{
  int idx = blockIdx.x * 256 + threadIdx.x;
  int c = idx & 63;
  float th = O4[idx];
  Z4[idx] = (_Float16)(qab[2 * c] * cosf(th) + qab[2 * c + 1] * sinf(th));
}

// fp32 -> fp16, 8 elements/thread
__global__ __launch_bounds__(256) void cvt_f2h(const float* __restrict__ in,
                                               half_t* __restrict__ outp, long n)
{
  long i = ((long)blockIdx.x * 256 + threadIdx.x) * 8;
  if (i >= n) return;
  float4 a = *(const float4*)(in + i);
  float4 b = *(const float4*)(in + i + 4);
  half8 h = {(_Float16)a.x, (_Float16)a.y, (_Float16)a.z, (_Float16)a.w,
             (_Float16)b.x, (_Float16)b.y, (_Float16)b.z, (_Float16)b.w};
  *(half8*)(outp + i) = h;
}

// Wqk[r][e]: r<1024 -> Wq row r, else Wk row r-1024 (fp16). 8 elts/thread.
__global__ __launch_bounds__(256) void pack_wqk(const float* __restrict__ Wq,
                                                const float* __restrict__ Wk,
                                                half_t* __restrict__ outp)
{
  long i = ((long)blockIdx.x * 256 + threadIdx.x) * 8;   // over 2048*1024
  int r = (int)(i >> 10);
  int e = (int)(i & 1023);
  const float* src = (r < 1024 ? Wq + (long)r * 1024
                               : Wk + (long)(r - 1024) * 1024) + e;
  float4 a = *(const float4*)src;
  float4 b = *(const float4*)(src + 4);
  half8 h = {(_Float16)a.x, (_Float16)a.y, (_Float16)a.z, (_Float16)a.w,
             (_Float16)b.x, (_Float16)b.y, (_Float16)b.z, (_Float16)b.w};
  *(half8*)(outp + i) = h;
}

// Wv4[c][e] = Wv[(c>>2)*64 + (c&3)][e] fp16, 64x1024, 8 elts/thread.
__global__ __launch_bounds__(256) void pack_wv4(const float* __restrict__ Wv,
                                                half_t* __restrict__ outp)
{
  long i = ((long)blockIdx.x * 256 + threadIdx.x) * 8;   // over 64*1024
  int c = (int)(i >> 10);
  int e = (int)(i & 1023);
  const float* src = Wv + (long)(((c >> 2) << 6) | (c & 3)) * 1024 + e;
  float4 a = *(const float4*)src;
  float4 b = *(const float4*)(src + 4);
  half8 h = {(_Float16)a.x, (_Float16)a.y, (_Float16)a.z, (_Float16)a.w,
             (_Float16)b.x, (_Float16)b.y, (_Float16)b.z, (_Float16)b.w};
  *(half8*)(outp + i) = h;
}

// Wos[e][c] = Wo[e][(c>>2)*64 + (c&3)] fp16.
__global__ __launch_bounds__(256) void pack_wo(const float* __restrict__ Wo,
                                               half_t* __restrict__ outp)
{
  int idx = blockIdx.x * 256 + threadIdx.x;   // 1024*64
  int e = idx >> 6, c = idx & 63;
  outp[idx] = (_Float16)Wo[(long)e * 1024 + (((c >> 2) << 6) | (c & 3))];
}

// ---------------------------------------------------------------------------
extern "C" void kernel_launch(void* const* d_in, const int* in_sizes, int n_in,
                              void* d_out, int out_size, void* d_ws, size_t ws_size,
                              hipStream_t stream)
{
  const float* x  = (const float*)d_in[0];
  const float* Wq = (const float*)d_in[1];
  const float* Wk = (const float*)d_in[2];
  const float* Wv = (const float*)d_in[3];
  const float* Wo = (const float*)d_in[4];
  const float* qp = (const float*)d_in[5];
  const int L = in_sizes[5] / 64;     // H*NQ = 64
  float* out = (float*)d_out;

  // B=4, T=2048, E=1024, H=16, hd=64, NQ=4; 8192 tokens.
  char* w = (char*)d_ws;
  size_t off = 0;
  auto alloc = [&](size_t bytes) -> void* {
    void* p = w + off;
    off = (off + bytes + 255) & ~(size_t)255;
    return p;
  };
  float*  qab  = (float*)alloc(512);
  half_t* xh   = (half_t*)alloc((size_t)8192 * 1024 * 2);
  half_t* Wqk  = (half_t*)alloc((size_t)2048 * 1024 * 2);
  half_t* Wv4  = (half_t*)alloc((size_t)64 * 1024 * 2);
  half_t* Wos  = (half_t*)alloc((size_t)1024 * 64 * 2);
  float*  V4tf = (float*)alloc((size_t)64 * 8192 * 4);
  half_t* V4th = (half_t*)alloc((size_t)64 * 8192 * 2);
  float*  O4   = (float*)alloc((size_t)8192 * 64 * 4);
  half_t* Z4   = (half_t*)alloc((size_t)8192 * 64 * 2);

  // QK projections (fp16, [8192][2048]: cols 0..1023 = Q, 1024..2047 = K)
  // live in d_out (exactly 33.55 MB fp32); consumed before final GEMM.
  half_t* QKb = (half_t*)d_out;

  // S (fp16 scores/probs in place): tier 0 = all batches (33.5 MB),
  // tier 1 = per-batch (8.4 MB), tier 2 = 512 rows (2.1 MB).
  int tier;
  if      (ws_size >= off + (size_t)8192 * 2048 * 2 + 256) tier = 0;
  else if (ws_size >= off + (size_t)2048 * 2048 * 2 + 256) tier = 1;
  else                                                     tier = 2;
  const size_t Sn = (tier == 0) ? (size_t)8192 * 2048
                  : (tier == 1) ? (size_t)2048 * 2048 : (size_t)512 * 2048;
  half_t* S = (half_t*)alloc(Sn * 2);

  // --- prep ---
  quantum_prep<<<dim3(1), dim3(64), 0, stream>>>(qp, qab, L);
  cvt_f2h<<<dim3(4096), dim3(256), 0, stream>>>(x, xh, (long)8192 * 1024);
  pack_wqk<<<dim3(1024), dim3(256), 0, stream>>>(Wq, Wk, Wqk);
  pack_wv4<<<dim3(32), dim3(256), 0, stream>>>(Wv, Wv4);
  pack_wo<<<dim3(256), dim3(256), 0, stream>>>(Wo, Wos);
  hipMemsetAsync(V4tf, 0, (size_t)64 * 8192 * 4, stream);
  hipMemsetAsync(O4, 0, (size_t)8192 * 64 * 4, stream);

  // --- QK projection: [Q|K] = xh @ Wqk^T  (8192 x 2048, K=1024) ---
  gemm_nt<128, 0><<<dim3(64, 16, 1), 256, 0, stream>>>(
      xh, Wqk, QKb, 1024, 1024, 2048, 16, 0,
      0, 0, 0, 0, 0, 0, 1.f);
  // --- V4 projection, split-K=4, transposed atomics into V4tf[64][8192] ---
  gemm_nt<64, 4><<<dim3(64, 1, 4), 256, 0, stream>>>(
      xh, Wv4, V4tf, 1024, 1024, 8192, 4, 0,
      0, 0, 0, 256, 256, 0, 1.f);
  cvt_f2h<<<dim3(256), dim3(256), 0, stream>>>(V4tf, V4th, (long)64 * 8192);

  if (tier == 0) {
    // scores all batches -> fp16 S: grid (16,16,4), z = batch
    gemm_nt<128, 0><<<dim3(16, 16, 4), 256, 0, stream>>>(
        QKb, QKb + 1024, S, 2048, 2048, 2048, 16, 0,
        0, 0, 0, (long)2048 * 2048, (long)2048 * 2048, (long)2048 * 2048,
        0.03125f);
    softmax_rows<<<dim3(8192), dim3(256), 0, stream>>>(S, 2048);
    // PV: grid (16,1,32), z = batch*8 + split (zShift=3), 256 k per split
    gemm_nt<64, 3><<<dim3(16, 1, 32), 256, 0, stream>>>(
        S, V4th, O4, 2048, 8192, 64, 4, 3,
        256, 256, 0, (long)2048 * 2048, 2048, (long)2048 * 64, 1.f);
  } else {
    const int R = (tier == 1) ? 2048 : 512;
    for (int row0 = 0; row0 < 8192; row0 += R) {
      const int b = row0 >> 11;
      gemm_nt<128, 0><<<dim3(R / 128, 16, 1), 256, 0, stream>>>(
          QKb + (long)row0 * 2048, QKb + 1024 + (long)b * 2048 * 2048, S,
          2048, 2048, 2048, 16, 0, 0, 0, 0, 0, 0, 0, 0.03125f);
      softmax_rows<<<dim3(R), dim3(256), 0, stream>>>(S, 2048);
      gemm_nt<64, 3><<<dim3(R / 128, 1, 8), 256, 0, stream>>>(
          S, V4th + (long)b * 2048, O4 + (long)row0 * 64,
          2048, 8192, 64, 4, 3, 256, 256, 0, 0, 0, 0, 1.f);
    }
  }

  // quantum elementwise + final out = Z4 @ Wos^T (K=64, fp32 store)
  quantum_z<<<dim3(2048), dim3(256), 0, stream>>>(O4, qab, Z4);
  gemm_nt<128, 2><<<dim3(64, 8, 1), 256, 0, stream>>>(
      Z4, Wos, out, 64, 64, 1024, 1, 0, 0, 0, 0, 0, 0, 0, 1.f);
}

// Round 6
// 263.093 us; speedup vs baseline: 1.4884x; 1.0685x over previous
//
#include <hip/hip_runtime.h>
#include <hip/hip_fp16.h>

typedef _Float16 half_t;
typedef __attribute__((ext_vector_type(8))) _Float16 half8;
typedef __attribute__((ext_vector_type(4))) float floatx4;

// async global->LDS, 16B/lane. LDS base must be wave-uniform; HW adds lane*16.
__device__ __forceinline__ void async_copy16(const void* src, void* dst_lds) {
  __builtin_amdgcn_global_load_lds(
      (__attribute__((address_space(1))) void*)src,
      (__attribute__((address_space(3))) void*)dst_lds, 16, 0, 0);
}

// ---------------------------------------------------------------------------
// NT GEMM: C[M x N] = A[M x K] * B[N x K]^T, fp16 in, fp32 accum
// (mfma 16x16x32). BM=128, BN in {64,128}. 256 thr = 4 waves (2x2).
// BK=64, XOR-swizzled LDS (chunk = logical ^ (row&7)): 0 bank conflicts.
// EPI: 0 = fp16 store*scale, 1 = fp16 transposed store (C[col*ldc+row]),
//      2 = f32 store*scale, 5 = quantum fp16 store:
//          C[..] = (fp16)(qab[2c]*cos(v) + qab[2c+1]*sin(v)).
// z: z2 = z>>zShift, z1 = z & mask; offsets z1*s?z1 + z2*s?z2 (elements).
template<int BN, int EPI>
__global__ __launch_bounds__(256) void gemm_nt(
    const half_t* __restrict__ A, const half_t* __restrict__ B,
    void* __restrict__ Cout,
    int lda, int ldb, int ldc, int kIters, int zShift,
    long sAz1, long sBz1, long sCz1,
    long sAz2, long sBz2, long sCz2, float scale,
    const float* __restrict__ qab)
{
  constexpr int BM = 128;
  constexpr int WN = BN / 2;          // wave tile N (64 or 32)
  constexpr int AN = WN / 16;         // acc blocks in N (4 or 2)
  constexpr int RA = BM * 8 / 256;    // A 16B-chunks per thread (4)
  constexpr int RB = BN * 8 / 256;    // B chunks per thread (4 or 2)
  __shared__ __align__(16) half_t lA[BM * 64];
  __shared__ __align__(16) half_t lB[BN * 64];

  const int tid  = threadIdx.x;
  const int wave = tid >> 6, lane = tid & 63;
  const int wm = wave >> 1, wn = wave & 1;
  const int er = lane >> 4, ec = lane & 15;   // k-quad / row-in-16
  const int sw = ec & 7;                      // read-side swizzle (row&7)

  const long z = blockIdx.z;
  const long z2 = z >> zShift;
  const long z1 = z - (z2 << zShift);
  const half_t* Ab = A + (long)blockIdx.x * BM * lda + z1 * sAz1 + z2 * sAz2;
  const half_t* Bb = B + (long)blockIdx.y * BN * ldb + z1 * sBz1 + z2 * sBz2;
  const long cz = z1 * sCz1 + z2 * sCz2;

  floatx4 acc[4][AN];
  #pragma unroll
  for (int i = 0; i < 4; i++)
    #pragma unroll
    for (int j = 0; j < AN; j++)
      acc[i][j] = (floatx4){0.f, 0.f, 0.f, 0.f};

  for (int ks = 0; ks < kIters; ++ks) {
    const half_t* Ak = Ab + ks * 64;
    const half_t* Bk = Bb + ks * 64;
    #pragma unroll
    for (int r = 0; r < RA; r++) {
      int s = r * 256 + tid;                  // LDS 16B slot
      int row = s >> 3;
      int kq = (s & 7) ^ (row & 7);           // swizzled source chunk
      async_copy16(Ak + (long)row * lda + kq * 8,
                   &lA[(r * 256 + wave * 64) * 8]);
    }
    #pragma unroll
    for (int r = 0; r < RB; r++) {
      int s = r * 256 + tid;
      int row = s >> 3;
      int kq = (s & 7) ^ (row & 7);
      async_copy16(Bk + (long)row * ldb + kq * 8,
                   &lB[(r * 256 + wave * 64) * 8]);
    }
    __syncthreads();   // drains vmcnt: LDS staged

    #pragma unroll
    for (int h = 0; h < 2; h++) {             // two 32-k sub-steps
      half8 af[4], bfv[AN];
      #pragma unroll
      for (int i = 0; i < 4; i++) {
        int row = wm * 64 + i * 16 + ec;
        af[i] = *(const half8*)&lA[row * 64 + (((h * 4 + er) ^ sw) * 8)];
      }
      #pragma unroll
      for (int j = 0; j < AN; j++) {
        int row = wn * WN + j * 16 + ec;
        bfv[j] = *(const half8*)&lB[row * 64 + (((h * 4 + er) ^ sw) * 8)];
      }
      #pragma unroll
      for (int i = 0; i < 4; i++)
        #pragma unroll
        for (int j = 0; j < AN; j++)
          acc[i][j] = __builtin_amdgcn_mfma_f32_16x16x32_f16(
              af[i], bfv[j], acc[i][j], 0, 0, 0);
    }
    __syncthreads();   // WAR before next stage
  }

  const long rowBase = (long)blockIdx.x * BM + wm * 64;
  const long colBase = (long)blockIdx.y * BN + wn * WN;
  #pragma unroll
  for (int i = 0; i < 4; i++)
    #pragma unroll
    for (int j = 0; j < AN; j++)
      #pragma unroll
      for (int r = 0; r < 4; r++) {
        long row = rowBase + i * 16 + er * 4 + r;   // C/D: row = quad*4+reg
        long col = colBase + j * 16 + ec;           // C/D: col = lane&15
        float v = acc[i][j][r];
        if constexpr (EPI == 0) {
          ((half_t*)Cout)[cz + row * (long)ldc + col] = (_Float16)(v * scale);
        } else if constexpr (EPI == 1) {
          ((half_t*)Cout)[cz + col * (long)ldc + row] = (_Float16)v;
        } else if constexpr (EPI == 2) {
          ((float*)Cout)[cz + row * (long)ldc + col] = v * scale;
        } else {   // EPI == 5: quantum transform on completed accumulator
          float za = qab[2 * (int)col], zb = qab[2 * (int)col + 1];
          float zv = za * cosf(v) + zb * sinf(v);
          ((half_t*)Cout)[cz + row * (long)ldc + col] = (_Float16)zv;
        }
      }
}

// ---------------------------------------------------------------------------
// In-place row softmax over 2048 fp16 (row stride ld halves).
__global__ __launch_bounds__(256) void softmax_rows(half_t* __restrict__ S,
                                                    int ld)
{
  const long row = blockIdx.x;
  half8* sp = (half8*)(S + row * (long)ld);
  const int t = threadIdx.x;
  const int wave = t >> 6, lane = t & 63;
  half8 hv = sp[t];
  float e[8];
  #pragma unroll
  for (int k = 0; k < 8; k++) e[k] = (float)hv[k];
  float m = e[0];
  #pragma unroll
  for (int k = 1; k < 8; k++) m = fmaxf(m, e[k]);
  #pragma unroll
  for (int o = 32; o > 0; o >>= 1) m = fmaxf(m, __shfl_xor(m, o));
  __shared__ float rmax[4], rsum[4];
  if (lane == 0) rmax[wave] = m;
  __syncthreads();
  m = fmaxf(fmaxf(rmax[0], rmax[1]), fmaxf(rmax[2], rmax[3]));
  float s = 0.f;
  #pragma unroll
  for (int k = 0; k < 8; k++) { e[k] = expf(e[k] - m); s += e[k]; }
  #pragma unroll
  for (int o = 32; o > 0; o >>= 1) s += __shfl_xor(s, o);
  if (lane == 0) rsum[wave] = s;
  __syncthreads();
  float inv = 1.f / (rsum[0] + rsum[1] + rsum[2] + rsum[3]);
  half8 o8;
  #pragma unroll
  for (int k = 0; k < 8; k++) o8[k] = (_Float16)(e[k] * inv);
  sp[t] = o8;
}

// ---------------------------------------------------------------------------
// ONE prep kernel (grid-partitioned):
//  [0,4096)      : cvt x fp32 -> fp16 (8 elts/thread)
//  [4096,5120)   : pack Wqk fp16  (rows 0..1023 = Wq, 1024..2047 = Wk)
//  [5120,5152)   : pack Wv4 fp16  (64 gathered rows of Wv)
//  [5152,5408)   : pack Wos fp16  (Wos[e][c] = Wo[e][gather(c)])
//  5408          : quantum circuit constants (A=<Z_q>, B=-<X_q> per head)
__global__ __launch_bounds__(256) void prep_all(
    const float* __restrict__ x,  const float* __restrict__ Wq,
    const float* __restrict__ Wk, const float* __restrict__ Wv,
    const float* __restrict__ Wo, const float* __restrict__ qp, int L,
    half_t* __restrict__ xh, half_t* __restrict__ Wqk,
    half_t* __restrict__ Wv4, half_t* __restrict__ Wos,
    float* __restrict__ qab)
{
  const int bid = blockIdx.x;
  if (bid < 4096) {                      // x -> fp16
    long i = ((long)bid * 256 + threadIdx.x) * 8;
    float4 a = *(const float4*)(x + i);
    float4 b = *(const float4*)(x + i + 4);
    half8 h = {(_Float16)a.x, (_Float16)a.y, (_Float16)a.z, (_Float16)a.w,
               (_Float16)b.x, (_Float16)b.y, (_Float16)b.z, (_Float16)b.w};
    *(half8*)(xh + i) = h;
  } else if (bid < 5120) {               // Wqk pack
    long i = ((long)(bid - 4096) * 256 + threadIdx.x) * 8;   // over 2048*1024
    int r = (int)(i >> 10);
    int e = (int)(i & 1023);
    const float* src = (r < 1024 ? Wq + (long)r * 1024
                                 : Wk + (long)(r - 1024) * 1024) + e;
    float4 a = *(const float4*)src;
    float4 b = *(const float4*)(src + 4);
    half8 h = {(_Float16)a.x, (_Float16)a.y, (_Float16)a.z, (_Float16)a.w,
               (_Float16)b.x, (_Float16)b.y, (_Float16)b.z, (_Float16)b.w};
    *(half8*)(Wqk + i) = h;
  } else if (bid < 5152) {               // Wv4 pack
    long i = ((long)(bid - 5120) * 256 + threadIdx.x) * 8;   // over 64*1024
    int c = (int)(i >> 10);
    int e = (int)(i & 1023);
    const float* src = Wv + (long)(((c >> 2) << 6) | (c & 3)) * 1024 + e;
    float4 a = *(const float4*)src;
    float4 b = *(const float4*)(src + 4);
    half8 h = {(_Float16)a.x, (_Float16)a.y, (_Float16)a.z, (_Float16)a.w,
               (_Float16)b.x, (_Float16)b.y, (_Float16)b.z, (_Float16)b.w};
    *(half8*)(Wv4 + i) = h;
  } else if (bid < 5408) {               // Wos pack
    int idx = (bid - 5152) * 256 + threadIdx.x;   // 1024*64
    int e = idx >> 6, c = idx & 63;
    Wos[idx] = (_Float16)Wo[(long)e * 1024 + (((c >> 2) << 6) | (c & 3))];
  } else {                               // quantum circuit constants
    int h = threadIdx.x;
    if (h >= 16) return;
    float st[16];
    #pragma unroll
    for (int i = 0; i < 16; i++) st[i] = 0.f;
    st[0] = 1.f;
    for (int l = 0; l < L; l++) {
      #pragma unroll
      for (int q = 0; q < 4; q++) {
        float th = qp[(h * L + l) * 4 + q];
        float c = cosf(0.5f * th), s = sinf(0.5f * th);
        int mq = 8 >> q;
        #pragma unroll
        for (int i = 0; i < 16; i++) {
          if ((i & mq) == 0) {
            float a0 = st[i], a1 = st[i | mq];
            st[i]      = c * a0 - s * a1;
            st[i | mq] = s * a0 + c * a1;
          }
        }
      }
      const int cm[4] = {8, 4, 2, 1};   // CNOT (0,1)(1,2)(2,3)(3,0)
      const int tm[4] = {4, 2, 1, 8};
      #pragma unroll
      for (int p = 0; p < 4; p++) {
        int mc = cm[p], mt = tm[p];
        #pragma unroll
        for (int i = 0; i < 16; i++) {
          if ((i & mc) != 0 && (i & mt) == 0) {
            float tv = st[i]; st[i] = st[i | mt]; st[i | mt] = tv;
          }
        }
      }
    }
    #pragma unroll
    for (int q = 0; q < 4; q++) {
      int mq = 8 >> q;
      float zc = 0.f, xc = 0.f;
      #pragma unroll
      for (int i = 0; i < 16; i++) {
        float p2 = st[i] * st[i];
        zc += ((i & mq) == 0) ? p2 : -p2;
        if ((i & mq) == 0) xc += st[i] * st[i | mq];
      }
      qab[(h * 4 + q) * 2 + 0] = zc;
      qab[(h * 4 + q) * 2 + 1] = -2.f * xc;
    }
  }
}

// ---------------------------------------------------------------------------
extern "C" void kernel_launch(void* const* d_in, const int* in_sizes, int n_in,
                              void* d_out, int out_size, void* d_ws, size_t ws_size,
                              hipStream_t stream)
{
  const float* x  = (const float*)d_in[0];
  const float* Wq = (const float*)d_in[1];
  const float* Wk = (const float*)d_in[2];
  const float* Wv = (const float*)d_in[3];
  const float* Wo = (const float*)d_in[4];
  const float* qp = (const float*)d_in[5];
  const int L = in_sizes[5] / 64;     // H*NQ = 64
  float* out = (float*)d_out;

  // B=4, T=2048, E=1024, H=16, hd=64, NQ=4; 8192 tokens.
  char* w = (char*)d_ws;
  size_t off = 0;
  auto alloc = [&](size_t bytes) -> void* {
    void* p = w + off;
    off = (off + bytes + 255) & ~(size_t)255;
    return p;
  };
  float*  qab  = (float*)alloc(512);
  half_t* xh   = (half_t*)alloc((size_t)8192 * 1024 * 2);
  half_t* Wqk  = (half_t*)alloc((size_t)2048 * 1024 * 2);
  half_t* Wv4  = (half_t*)alloc((size_t)64 * 1024 * 2);
  half_t* Wos  = (half_t*)alloc((size_t)1024 * 64 * 2);
  half_t* V4th = (half_t*)alloc((size_t)64 * 8192 * 2);   // [chan][token]
  half_t* Z4   = (half_t*)alloc((size_t)8192 * 64 * 2);

  // QK projections (fp16, [8192][2048]: cols 0..1023 = Q, 1024..2047 = K)
  // live in d_out (exactly 33.55 MB fp32); consumed before final GEMM.
  half_t* QKb = (half_t*)d_out;

  // S (fp16 scores/probs in place): tier 0 = all batches (33.5 MB),
  // else per-batch loop (8.4 MB).
  int tier = (ws_size >= off + (size_t)8192 * 2048 * 2 + 256) ? 0 : 1;
  const size_t Sn = (tier == 0) ? (size_t)8192 * 2048 : (size_t)2048 * 2048;
  half_t* S = (half_t*)alloc(Sn * 2);

  // --- 1 prep dispatch ---
  prep_all<<<dim3(5409), dim3(256), 0, stream>>>(
      x, Wq, Wk, Wv, Wo, qp, L, xh, Wqk, Wv4, Wos, qab);

  // --- QK projection: [Q|K] = xh @ Wqk^T  (8192 x 2048, K=1024) ---
  gemm_nt<128, 0><<<dim3(64, 16, 1), 256, 0, stream>>>(
      xh, Wqk, QKb, 1024, 1024, 2048, 16, 0,
      0, 0, 0, 0, 0, 0, 1.f, nullptr);
  // --- V4 projection -> V4th[64][8192] directly (transposed fp16 store) ---
  gemm_nt<64, 1><<<dim3(64, 1, 1), 256, 0, stream>>>(
      xh, Wv4, V4th, 1024, 1024, 8192, 16, 0,
      0, 0, 0, 0, 0, 0, 1.f, nullptr);

  if (tier == 0) {
    // scores all batches -> fp16 S: grid (16,16,4), z = batch
    gemm_nt<128, 0><<<dim3(16, 16, 4), 256, 0, stream>>>(
        QKb, QKb + 1024, S, 2048, 2048, 2048, 16, 0,
        0, 0, 0, (long)2048 * 2048, (long)2048 * 2048, (long)2048 * 2048,
        0.03125f, nullptr);
    softmax_rows<<<dim3(8192), dim3(256), 0, stream>>>(S, 2048);
    // PV + quantum epilogue -> Z4 fp16: grid (16,1,4), z = batch, K=2048
    gemm_nt<64, 5><<<dim3(16, 1, 4), 256, 0, stream>>>(
        S, V4th, Z4, 2048, 8192, 64, 32, 0,
        0, 0, 0, (long)2048 * 2048, 2048, (long)2048 * 64, 1.f, qab);
  } else {
    for (int b = 0; b < 4; b++) {
      const long q0 = (long)b * 2048;
      gemm_nt<128, 0><<<dim3(16, 16, 1), 256, 0, stream>>>(
          QKb + q0 * 2048, QKb + 1024 + q0 * 2048, S,
          2048, 2048, 2048, 16, 0, 0, 0, 0, 0, 0, 0, 0.03125f, nullptr);
      softmax_rows<<<dim3(2048), dim3(256), 0, stream>>>(S, 2048);
      gemm_nt<64, 5><<<dim3(16, 1, 1), 256, 0, stream>>>(
          S, V4th + q0, Z4 + q0 * 64, 2048, 8192, 64, 32, 0,
          0, 0, 0, 0, 0, 0, 1.f, qab);
    }
  }

  // final: out = Z4 @ Wos^T  (8192 x 1024, K=64, fp32 store)
  gemm_nt<128, 2><<<dim3(64, 8, 1), 256, 0, stream>>>(
      Z4, Wos, out, 64, 64, 1024, 1, 0, 0, 0, 0, 0, 0, 0, 1.f, nullptr);
}